// Round 8
// baseline (424.590 us; speedup 1.0000x reference)
//
#include <hip/hip_runtime.h>
#include <hip/hip_bf16.h>

typedef __attribute__((ext_vector_type(8))) short short8;
typedef __attribute__((ext_vector_type(4))) float floatx4;

#define N_ROWS 32768
#define D_DIM  128
#define H_KEYS 8192
#define C_COLS 100
#define BM     64       // rows per block; every wave covers all 64 rows
#define OL_STRIDE 116   // floats per OL row (116%32=20 -> <=2-way banks in epilogue)
#define LOG2E 1.4426950408889634f

// NOTE (hard-won): __launch_bounds__(256, w) caps ARCH VGPRs at 256/w; w>=3
// spilled (GBs of scratch traffic). CSV VGPR_Count excludes AGPRs. No waves
// arg here: never cap below need. ~230 regs -> 2 waves/SIMD, 8 waves/CU.

__device__ __forceinline__ unsigned short f2bf(float f) {
  union { float f; unsigned int u; } v; v.f = f;
  unsigned int r = v.u + 0x7fffu + ((v.u >> 16) & 1u);  // RNE
  return (unsigned short)(r >> 16);
}

// v_cvt_pk_bf16_f32: two fp32 -> packed bf16
__device__ __forceinline__ unsigned int pk2bf(float a, float b) {
  union { __hip_bfloat162 h; unsigned int u; } c;
  c.h = __float22bfloat162_rn(float2{a, b});
  return c.u;
}

// ---- merged prep: blocks [0,512) pack K (scaled) + ksq; [512,768) pack V ----
__global__ void prep_kernel(const float* __restrict__ keys,
                            const float* __restrict__ values,
                            const float* __restrict__ temp,
                            unsigned short* __restrict__ kp,
                            float* __restrict__ ksq,
                            unsigned short* __restrict__ vp) {
  int tid = threadIdx.x;
  if (blockIdx.x < 512) {
    // K pack (physical order): block rt covers key rows [16rt, 16rt+16).
    __shared__ float red[256];
    int rt = blockIdx.x;
    int lane = tid & 63;
    int c = tid >> 6;
    float scale = 2.0f * LOG2E / temp[0];
    int row = rt * 16 + (lane & 15);
    int d0 = c * 32 + (lane >> 4) * 8;
    const float* s = keys + (size_t)row * D_DIM + d0;
    float4 lo = *(const float4*)s;
    float4 hi = *(const float4*)(s + 4);
    float sq = lo.x*lo.x + lo.y*lo.y + lo.z*lo.z + lo.w*lo.w
             + hi.x*hi.x + hi.y*hi.y + hi.z*hi.z + hi.w*hi.w;
    red[c * 64 + lane] = sq;
    union { short8 v; unsigned int u[4]; } cv;
    cv.u[0] = pk2bf(lo.x * scale, lo.y * scale);
    cv.u[1] = pk2bf(lo.z * scale, lo.w * scale);
    cv.u[2] = pk2bf(hi.x * scale, hi.y * scale);
    cv.u[3] = pk2bf(hi.z * scale, hi.w * scale);
    *(short8*)(kp + ((size_t)(rt * 4 + c) * 64 + lane) * 8) = cv.v;
    __syncthreads();
    if (tid < 16) {
      float acc = 0.f;
#pragma unroll
      for (int cc = 0; cc < 4; ++cc)
#pragma unroll
        for (int qq = 0; qq < 4; ++qq)
          acc += red[cc * 64 + qq * 16 + tid];
      ksq[rt * 16 + tid] = -acc * LOG2E / temp[0];
    }
  } else {
    // V pack, PERMUTED within each 32-key group so the S-MFMA C/D output
    // (after exp2+pack) is directly the PV A-fragment:
    // A-slot k = q*8+j  <-  physical key  phi = (j>>2)*16 + q*4 + (j&3).
    // Pad to 112 cols; ones-column at col 100 = softmax denominator.
    __shared__ float vt[32 * 113];
    int g = blockIdx.x - 512;           // 32-key group
    for (int idx = tid; idx < 32 * 112; idx += 256) {
      int k = idx / 112, col = idx - k * 112;
      float val;
      if (col < C_COLS) val = values[(size_t)(g * 32 + k) * C_COLS + col];
      else val = (col == C_COLS) ? 1.0f : 0.0f;
      vt[k * 113 + col] = val;
    }
    __syncthreads();
    for (int u = tid; u < 7 * 64; u += 256) {
      int ct = u >> 6, l = u & 63;
      int n0 = l & 15, q = l >> 4;
      short8 o;
#pragma unroll
      for (int j = 0; j < 8; ++j) {
        int src = ((j >> 2) << 4) + q * 4 + (j & 3);   // phi(k)
        o[j] = (short)f2bf(vt[src * 113 + ct * 16 + n0]);
      }
      *(short8*)(vp + ((size_t)(g * 7 + ct) * 64 + l) * 8) = o;
    }
  }
}

// Fused RBF attention. Waves split KEYS 4-way (2048 each), every wave holds
// all 64 x-rows in registers and a partial O; register-resident P (V rows
// pre-permuted), NO LDS / NO barriers in the loop, no redundant K/V loads.
// One 4-phase LDS reduction + normalize at the end; output written final.
__global__ __launch_bounds__(256)
void attn_rbf_kernel(const float* __restrict__ x,
                     const unsigned short* __restrict__ kp,
                     const float* __restrict__ ksq,
                     const unsigned short* __restrict__ vp,
                     float* __restrict__ out) {
  __shared__ __align__(16) float OL[BM * OL_STRIDE + BM];  // 29,952 B
  float* rden = OL + BM * OL_STRIDE;

  const int tid = threadIdx.x;
  const int w = tid >> 6;       // wave 0..3 -> keys [2048w, 2048w+2048)
  const int lane = tid & 63;
  const int n0 = lane & 15;
  const int q = lane >> 4;
  const int b = blockIdx.x;     // rows [64b, 64b+64)

  // x rows (all 64) -> bf16 B-fragments in registers (64 VGPRs).
  short8 xf[4][4];
#pragma unroll
  for (int rt = 0; rt < 4; ++rt)
#pragma unroll
    for (int c = 0; c < 4; ++c) {
      const float* s = x + (size_t)(b * BM + rt * 16 + n0) * D_DIM + c * 32 + q * 8;
      float4 lo = *(const float4*)s;
      float4 hi = *(const float4*)(s + 4);
      union { short8 v; unsigned int u[4]; } cv;
      cv.u[0] = pk2bf(lo.x, lo.y);
      cv.u[1] = pk2bf(lo.z, lo.w);
      cv.u[2] = pk2bf(hi.x, hi.y);
      cv.u[3] = pk2bf(hi.z, hi.w);
      xf[rt][c] = cv.v;
    }

  floatx4 oacc[4][7];           // partial O over this wave's keys (112 regs)
#pragma unroll
  for (int rt = 0; rt < 4; ++rt)
#pragma unroll
    for (int ct = 0; ct < 7; ++ct)
      oacc[rt][ct] = (floatx4){0.f, 0.f, 0.f, 0.f};

  const int g0 = w * 64;        // first 32-key group of this wave
  for (int it = 0; it < 64; ++it) {
    const int g = g0 + it;

    floatx4 ksq4[2];
#pragma unroll
    for (int kt = 0; kt < 2; ++kt)
      ksq4[kt] = *(const floatx4*)(ksq + g * 32 + kt * 16 + q * 4);

    // ---- S^T = K . X^T per 16-key half (sequential kt to cap registers),
    //      C-init = -ksq*log2e/T; exp2 packs straight into PV A-fragments.
    union { short8 v; unsigned int u[4]; } pu[4];
#pragma unroll
    for (int kt = 0; kt < 2; ++kt) {
      short8 kf[4];
#pragma unroll
      for (int c = 0; c < 4; ++c)
        kf[c] = *(const short8*)(kp + ((size_t)((g * 2 + kt) * 4 + c) * 64 + lane) * 8);
      floatx4 s[4];
#pragma unroll
      for (int rt = 0; rt < 4; ++rt) s[rt] = ksq4[kt];
#pragma unroll
      for (int c = 0; c < 4; ++c)
#pragma unroll
        for (int rt = 0; rt < 4; ++rt)
          s[rt] = __builtin_amdgcn_mfma_f32_16x16x32_bf16(kf[c], xf[rt][c], s[rt], 0, 0, 0);
#pragma unroll
      for (int rt = 0; rt < 4; ++rt) {
        pu[rt].u[kt * 2 + 0] = pk2bf(__builtin_amdgcn_exp2f(s[rt][0]), __builtin_amdgcn_exp2f(s[rt][1]));
        pu[rt].u[kt * 2 + 1] = pk2bf(__builtin_amdgcn_exp2f(s[rt][2]), __builtin_amdgcn_exp2f(s[rt][3]));
      }
    }

    // ---- O += P . V (V rows pre-permuted to match pf's key order) ----
#pragma unroll
    for (int ct = 0; ct < 7; ++ct) {
      short8 vf = *(const short8*)(vp + ((size_t)(g * 7 + ct) * 64 + lane) * 8);
#pragma unroll
      for (int rt = 0; rt < 4; ++rt)
        oacc[rt][ct] = __builtin_amdgcn_mfma_f32_16x16x32_bf16(pu[rt].v, vf, oacc[rt][ct], 0, 0, 0);
    }
  }

  // ---- cross-wave O reduction in LDS (4 phases), normalize, store ----
#pragma unroll
  for (int ph = 0; ph < 4; ++ph) {
    if (w == ph) {
#pragma unroll
      for (int rt = 0; rt < 4; ++rt)
#pragma unroll
        for (int ct = 0; ct < 7; ++ct)
#pragma unroll
          for (int i = 0; i < 4; ++i) {
            int a = (rt * 16 + q * 4 + i) * OL_STRIDE + ct * 16 + n0;
            if (ph == 0) OL[a] = oacc[rt][ct][i];
            else         OL[a] += oacc[rt][ct][i];
          }
    }
    __syncthreads();
  }
  if (tid < BM) rden[tid] = 1.0f / OL[tid * OL_STRIDE + 100];
  __syncthreads();

  float* outb = out + (size_t)b * (BM * C_COLS);
  for (int idx = tid; idx < BM * C_COLS; idx += 256) {
    int n = idx / C_COLS;
    int cc = idx - n * C_COLS;
    outb[idx] = OL[n * OL_STRIDE + cc] * rden[n];
  }
}

extern "C" void kernel_launch(void* const* d_in, const int* in_sizes, int n_in,
                              void* d_out, int out_size, void* d_ws, size_t ws_size,
                              hipStream_t stream) {
  (void)in_sizes; (void)n_in; (void)out_size; (void)ws_size;
  const float* x      = (const float*)d_in[0];
  const float* keys   = (const float*)d_in[1];
  const float* values = (const float*)d_in[2];
  const float* temp   = (const float*)d_in[3];
  float* out = (float*)d_out;

  char* ws = (char*)d_ws;
  unsigned short* kp  = (unsigned short*)(ws);              //  2,097,152 B
  unsigned short* vp  = (unsigned short*)(ws + 2097152);    //  1,835,008 B
  float*          ksq = (float*)(ws + 3932160);             //     32,768 B

  hipLaunchKernelGGL(prep_kernel,     dim3(768), dim3(256), 0, stream,
                     keys, values, temp, kp, ksq, vp);
  hipLaunchKernelGGL(attn_rbf_kernel, dim3(512), dim3(256), 0, stream,
                     x, kp, ksq, vp, out);
}